// Round 18
// baseline (458.330 us; speedup 1.0000x reference)
//
#include <hip/hip_runtime.h>

#define NN 100000
#define NE 1600000
#define CH 4096                                  // edges per chunk
#define NCHUNK ((NE + CH - 1) / CH)              // 391
#define BK 128                                   // nodes per bucket
#define NBUCK ((NN + BK - 1) / BK)               // 782 (128-node buckets = fused blocks)

__device__ __forceinline__ float wave_red(float v) {
#pragma unroll
    for (int off = 32; off > 0; off >>= 1) v += __shfl_down(v, off, 64);
    return v;
}

// ---------------- build phase: bucket sort, zero global atomics --------------
__global__ __launch_bounds__(256) void hist_kernel(
    const int* __restrict__ ei, int* __restrict__ hist)
{
    __shared__ int h[NBUCK];
    int t = threadIdx.x, c = blockIdx.x;
    for (int b = t; b < NBUCK; b += 256) h[b] = 0;
    __syncthreads();
    int base = c * CH;
    for (int i = t; i < CH; i += 256) {
        int e = base + i;
        if (e < NE) atomicAdd(&h[ei[e] >> 7], 1);
    }
    __syncthreads();
    for (int b = t; b < NBUCK; b += 256) hist[c * NBUCK + b] = h[b];
}

__global__ __launch_bounds__(512) void bscan_kernel(
    const int* __restrict__ hist, int* __restrict__ baseT, int* __restrict__ colTotal)
{
    __shared__ int buf[2][512];
    int b = blockIdx.x, t = threadIdx.x;
    int v = (t < NCHUNK) ? hist[t * NBUCK + b] : 0;
    buf[0][t] = v;
    __syncthreads();
    int src = 0;
    for (int d = 1; d < 512; d <<= 1) {
        int nv = buf[src][t] + ((t >= d) ? buf[src][t - d] : 0);
        buf[src ^ 1][t] = nv;
        src ^= 1;
        __syncthreads();
    }
    if (t < NCHUNK) baseT[b * NCHUNK + t] = buf[src][t] - v;   // exclusive over chunks
    if (t == NCHUNK - 1) colTotal[b] = buf[src][t];
}

__global__ __launch_bounds__(1024) void boff_kernel(
    const int* __restrict__ colTotal, int* __restrict__ b_off)
{
    __shared__ int buf[2][1024];
    int t = threadIdx.x;
    int v = (t < NBUCK) ? colTotal[t] : 0;
    buf[0][t] = v;
    __syncthreads();
    int src = 0;
    for (int d = 1; d < 1024; d <<= 1) {
        int nv = buf[src][t] + ((t >= d) ? buf[src][t - d] : 0);
        buf[src ^ 1][t] = nv;
        src ^= 1;
        __syncthreads();
    }
    if (t < NBUCK) b_off[t] = buf[src][t] - v;
    if (t == NBUCK - 1) b_off[NBUCK] = buf[src][t];            // = NE
}

__global__ __launch_bounds__(256) void fillb_kernel(
    const int* __restrict__ ei, const float* __restrict__ eattr,
    const int* __restrict__ baseT, const int* __restrict__ b_off,
    float4* __restrict__ rec)
{
    __shared__ int sslot[NBUCK];
    int t = threadIdx.x, c = blockIdx.x;
    for (int b = t; b < NBUCK; b += 256)
        sslot[b] = b_off[b] + baseT[b * NCHUNK + c];
    __syncthreads();
    int base = c * CH;
    for (int i = t; i < CH; i += 256) {
        int e = base + i;
        if (e < NE) {
            int row = ei[e];
            int slot = atomicAdd(&sslot[row >> 7], 1);
            float2 ea = reinterpret_cast<const float2*>(eattr)[e];
            float4 v;
            v.x = __int_as_float(row);
            v.y = __int_as_float(ei[NE + e]);
            v.z = ea.x; v.w = ea.y;
            rec[slot] = v;
        }
    }
}

// ---- P precompute for layer 0: Pr[i]=x[i]@W1[1:9], Pc[i]=x[i]@W1[9:17] ------
__global__ __launch_bounds__(256) void prep_kernel(
    const float* __restrict__ x, const float* __restrict__ W1,
    float* __restrict__ Pr, float* __restrict__ Pc)
{
    int i = blockIdx.x * 256 + threadIdx.x;
    if (i >= NN) return;
    const float4* xi = reinterpret_cast<const float4*>(x + (size_t)i * 8);
    float4 a0 = xi[0], a1 = xi[1];
    float xv[8] = {a0.x, a0.y, a0.z, a0.w, a1.x, a1.y, a1.z, a1.w};
    float pr[16], pc[16];
#pragma unroll
    for (int q = 0; q < 16; q++) { pr[q] = 0.f; pc[q] = 0.f; }
#pragma unroll
    for (int k = 0; k < 8; k++) {
        float v = xv[k];
#pragma unroll
        for (int q = 0; q < 16; q++) {
            pr[q] += v * W1[(1 + k) * 16 + q];
            pc[q] += v * W1[(9 + k) * 16 + q];
        }
    }
    float4* po = reinterpret_cast<float4*>(Pr + (size_t)i * 16);
#pragma unroll
    for (int t = 0; t < 4; t++)
        po[t] = make_float4(pr[4 * t], pr[4 * t + 1], pr[4 * t + 2], pr[4 * t + 3]);
    float4* qo = reinterpret_cast<float4*>(Pc + (size_t)i * 16);
#pragma unroll
    for (int t = 0; t < 4; t++)
        qo[t] = make_float4(pc[4 * t], pc[4 * t + 1], pc[4 * t + 2], pc[4 * t + 3]);
}

// ============ FUSED layer kernel: edge MLP + LDS Pr window + node MLP ========
// 128-node buckets -> 782 blocks (~3/CU, ~12 waves/CU) so the Pc random-gather
// latency has waves to hide behind (r17's 391-block grid sat at 10% occupancy).
template <bool WRITE_REC, bool NEED_SUM, bool HAS_NEXT>
__global__ __launch_bounds__(256, 4) void fused_kernel(
    float4* __restrict__ rec, const int* __restrict__ b_off,
    const float* __restrict__ PrIn, const float* __restrict__ PcIn,
    const float* __restrict__ gptr,
    const float* __restrict__ eW1, const float* __restrict__ eB1,
    const float* __restrict__ eW2, const float* __restrict__ eB2,
    const float* __restrict__ x,
    const float* __restrict__ nW1, const float* __restrict__ nB1,
    const float* __restrict__ nW2, const float* __restrict__ nB2,
    const float* __restrict__ nextW1,
    float* __restrict__ PrOut, float* __restrict__ PcOut,
    float* __restrict__ xout, float* __restrict__ sums)
{
    __shared__ float sPrT[16 * BK];              // 8 KB, transposed
    __shared__ float sagg[BK][2];
    __shared__ float redE[4][2];
    __shared__ float redN[4][8];
    int tid = threadIdx.x;
    if (tid < BK) { sagg[tid][0] = 0.f; sagg[tid][1] = 0.f; }

    int n0 = blockIdx.x * BK;
    if (tid < BK) {
        int nrow = n0 + tid;
        if (nrow < NN) {
            const float4* ps = reinterpret_cast<const float4*>(PrIn + (size_t)nrow * 16);
            float4 p0 = ps[0], p1 = ps[1], p2 = ps[2], p3 = ps[3];
            sPrT[0 * BK + tid]  = p0.x; sPrT[1 * BK + tid]  = p0.y;
            sPrT[2 * BK + tid]  = p0.z; sPrT[3 * BK + tid]  = p0.w;
            sPrT[4 * BK + tid]  = p1.x; sPrT[5 * BK + tid]  = p1.y;
            sPrT[6 * BK + tid]  = p1.z; sPrT[7 * BK + tid]  = p1.w;
            sPrT[8 * BK + tid]  = p2.x; sPrT[9 * BK + tid]  = p2.y;
            sPrT[10 * BK + tid] = p2.z; sPrT[11 * BK + tid] = p2.w;
            sPrT[12 * BK + tid] = p3.x; sPrT[13 * BK + tid] = p3.y;
            sPrT[14 * BK + tid] = p3.z; sPrT[15 * BK + tid] = p3.w;
        }
    }
    __syncthreads();

    int e0 = b_off[blockIdx.x], e1 = b_off[blockIdx.x + 1];

    float gval = gptr[0];
    float gterm[16];
#pragma unroll
    for (int q = 0; q < 16; q++) gterm[q] = eB1[q] + gval * eW1[q];

    float t0 = 0.f, t1 = 0.f;
    for (int e = e0 + tid; e < e1; e += 256) {
        float4 r = rec[e];
        int row = __float_as_int(r.x);
        int col = __float_as_int(r.y);
        float ea0 = r.z, ea1 = r.w;
        int li = row - n0;
        const float4* pc = reinterpret_cast<const float4*>(PcIn + (size_t)col * 16);
        float4 c0 = pc[0], c1 = pc[1], c2 = pc[2], c3 = pc[3];
        float h[16];
#pragma unroll
        for (int q = 0; q < 16; q++) h[q] = gterm[q] + sPrT[q * BK + li];
        h[0]  += c0.x; h[1]  += c0.y; h[2]  += c0.z; h[3]  += c0.w;
        h[4]  += c1.x; h[5]  += c1.y; h[6]  += c1.z; h[7]  += c1.w;
        h[8]  += c2.x; h[9]  += c2.y; h[10] += c2.z; h[11] += c2.w;
        h[12] += c3.x; h[13] += c3.y; h[14] += c3.z; h[15] += c3.w;
#pragma unroll
        for (int q = 0; q < 16; q++) {
            h[q] += ea0 * eW1[17 * 16 + q];
            h[q] += ea1 * eW1[18 * 16 + q];
        }
        float s0 = eB2[0], s1 = eB2[1];
#pragma unroll
        for (int q = 0; q < 16; q++) {
            float rr = fmaxf(h[q], 0.f);
            s0 += rr * eW2[2 * q];
            s1 += rr * eW2[2 * q + 1];
        }
        if (WRITE_REC) {
            float4 w;
            w.x = r.x; w.y = r.y; w.z = s0; w.w = s1;
            rec[e] = w;
        }
        atomicAdd(&sagg[li][0], s0);
        atomicAdd(&sagg[li][1], s1);
        t0 += s0; t1 += s1;
    }

    if (NEED_SUM) {
        float r0 = wave_red(t0);
        float r1 = wave_red(t1);
        int wave = tid >> 6, lane = tid & 63;
        if (lane == 0) { redE[wave][0] = r0; redE[wave][1] = r1; }
    }
    __syncthreads();   // sagg complete (and redE visible)
    if (NEED_SUM && tid == 0) {
        atomicAdd(&sums[0], redE[0][0] + redE[1][0] + redE[2][0] + redE[3][0]);
        atomicAdd(&sums[1], redE[0][1] + redE[1][1] + redE[2][1] + redE[3][1]);
    }

    // ---------------- phase 2: node MLP (threads 0..BK-1) ----------------
    int n = n0 + tid;
    float out[8];
#pragma unroll
    for (int m = 0; m < 8; m++) out[m] = 0.f;

    if (tid < BK && n < NN) {
        float in[11];
        in[0] = gval;
        const float4* xi = reinterpret_cast<const float4*>(x + (size_t)n * 8);
        float4 a0 = xi[0], a1 = xi[1];
        in[1] = a0.x; in[2] = a0.y; in[3] = a0.z; in[4] = a0.w;
        in[5] = a1.x; in[6] = a1.y; in[7] = a1.z; in[8] = a1.w;
        in[9] = sagg[tid][0]; in[10] = sagg[tid][1];

        float h[16];
#pragma unroll
        for (int q = 0; q < 16; q++) h[q] = nB1[q];
#pragma unroll
        for (int k = 0; k < 11; k++) {
            float v = in[k];
#pragma unroll
            for (int q = 0; q < 16; q++) h[q] += v * nW1[k * 16 + q];
        }
#pragma unroll
        for (int m = 0; m < 8; m++) out[m] = nB2[m];
#pragma unroll
        for (int q = 0; q < 16; q++) {
            float hq = fmaxf(h[q], 0.f);
#pragma unroll
            for (int m = 0; m < 8; m++) out[m] += hq * nW2[q * 8 + m];
        }
        float4* xo = reinterpret_cast<float4*>(xout + (size_t)n * 8);
        xo[0] = make_float4(out[0], out[1], out[2], out[3]);
        xo[1] = make_float4(out[4], out[5], out[6], out[7]);

        if (HAS_NEXT) {
            float pr[16], pc[16];
#pragma unroll
            for (int q = 0; q < 16; q++) { pr[q] = 0.f; pc[q] = 0.f; }
#pragma unroll
            for (int k = 0; k < 8; k++) {
                float v = out[k];
#pragma unroll
                for (int q = 0; q < 16; q++) {
                    pr[q] += v * nextW1[(1 + k) * 16 + q];
                    pc[q] += v * nextW1[(9 + k) * 16 + q];
                }
            }
            float4* po = reinterpret_cast<float4*>(PrOut + (size_t)n * 16);
#pragma unroll
            for (int t = 0; t < 4; t++)
                po[t] = make_float4(pr[4*t], pr[4*t+1], pr[4*t+2], pr[4*t+3]);
            float4* qo = reinterpret_cast<float4*>(PcOut + (size_t)n * 16);
#pragma unroll
            for (int t = 0; t < 4; t++)
                qo[t] = make_float4(pc[4*t], pc[4*t+1], pc[4*t+2], pc[4*t+3]);
        }
    }
    if (NEED_SUM) {
        float r[8];
#pragma unroll
        for (int m = 0; m < 8; m++) r[m] = wave_red(out[m]);
        int wave = tid >> 6, lane = tid & 63;
        if (lane == 0) {
#pragma unroll
            for (int m = 0; m < 8; m++) redN[wave][m] = r[m];
        }
        __syncthreads();
        if (tid == 0) {
#pragma unroll
            for (int m = 0; m < 8; m++) {
                float s = redN[0][m] + redN[1][m] + redN[2][m] + redN[3][m];
                atomicAdd(&sums[2 + m], s);
            }
        }
    }
}

// ---------------- global block: MLP(11->16->1), single thread ----------------
__global__ void glob_kernel(const float* __restrict__ sums,
                            const float* __restrict__ gold,
                            const float* __restrict__ W1, const float* __restrict__ B1,
                            const float* __restrict__ W2, const float* __restrict__ B2,
                            float* __restrict__ gnew)
{
    if (threadIdx.x == 0 && blockIdx.x == 0) {
        float in[11];
#pragma unroll
        for (int j = 0; j < 8; j++) in[j] = sums[2 + j] * (1.0f / NN);
        in[8] = sums[0] * (1.0f / NE);
        in[9] = sums[1] * (1.0f / NE);
        in[10] = gold[0];
        float acc = B2[0];
#pragma unroll
        for (int j = 0; j < 16; j++) {
            float h = B1[j];
#pragma unroll
            for (int k = 0; k < 11; k++) h += in[k] * W1[k * 16 + j];
            acc += fmaxf(h, 0.f) * W2[j];
        }
        gnew[0] = acc;
    }
}

extern "C" void kernel_launch(void* const* d_in, const int* in_sizes, int n_in,
                              void* d_out, int out_size, void* d_ws, size_t ws_size,
                              hipStream_t stream) {
    const float* x     = (const float*)d_in[0];
    const int*   ei    = (const int*)d_in[1];
    const float* eattr = (const float*)d_in[2];
    const float* g     = (const float*)d_in[3];
    const float* eW1 = (const float*)d_in[4];
    const float* eB1 = (const float*)d_in[5];
    const float* eW2 = (const float*)d_in[6];
    const float* eB2 = (const float*)d_in[7];
    const float* nW1 = (const float*)d_in[8];
    const float* nB1 = (const float*)d_in[9];
    const float* nW2 = (const float*)d_in[10];
    const float* nB2 = (const float*)d_in[11];
    const float* gW1 = (const float*)d_in[12];
    const float* gB1 = (const float*)d_in[13];
    const float* gW2 = (const float*)d_in[14];
    const float* gB2 = (const float*)d_in[15];
    float* out = (float*)d_out;

    char* ws = (char*)d_ws;
    float*  xb0    = (float*)(ws);                 // 3,200,000
    int*    b_off  = (int*)  (ws + 3200000);       // 783*4 -> pad 3,200
    float*  sums   = (float*)(ws + 3203200);       // 2 slabs x 16 + g1/g2
    float*  g1     = (float*)(ws + 3203328);
    float*  g2     = g1 + 1;
    float4* rec    = (float4*)(ws + 3203392);      // 25,600,000 -> 28,803,392
    float*  PrA    = (float*)(ws + 28803392);      // 6,400,000 -> 35,203,392
    float*  PcA    = (float*)(ws + 35203392);      // 6,400,000 -> 41,603,392
    float*  PrB    = (float*)(ws + 41603392);      // 6,400,000 -> 48,003,392
    float*  PcB    = (float*)(ws + 48003392);      // 6,400,000 -> 54,403,392
    // build-phase temporaries alias PrB (dead until fused L0 phase 2):
    int*    hist     = (int*)PrB;                        // 391*782*4 = 1,223,048
    int*    baseT    = (int*)((char*)PrB + 1223168);     // 1,223,048
    int*    colTotal = (int*)((char*)PrB + 2446336);     // 3,128

    dim3 blk(256);
    dim3 cgrid(NCHUNK);                            // 391 chunks
    dim3 bgrid(NBUCK);                             // 782 buckets
    dim3 ngrid((NN + 255) / 256);                  // 391

    // ---- bucket-sort build (no global atomics) ----
    hipMemsetAsync(sums, 0, 192, stream);
    hist_kernel<<<cgrid, blk, 0, stream>>>(ei, hist);
    bscan_kernel<<<bgrid, 512, 0, stream>>>(hist, baseT, colTotal);
    boff_kernel<<<1, 1024, 0, stream>>>(colTotal, b_off);
    fillb_kernel<<<cgrid, blk, 0, stream>>>(ei, eattr, baseT, b_off, rec);
    prep_kernel<<<ngrid, blk, 0, stream>>>(x, eW1, PrA, PcA);

    // ---- layer 0: P=A -> writes P=B; rec.zw: ea -> L0 edge emb; x -> xb0 ----
    fused_kernel<true, true, true><<<bgrid, blk, 0, stream>>>(
        rec, b_off, PrA, PcA, g,
        eW1, eB1, eW2, eB2,
        x, nW1, nB1, nW2, nB2,
        eW1 + 304, PrB, PcB, xb0, sums);
    glob_kernel<<<1, 64, 0, stream>>>(sums, g, gW1, gB1, gW2, gB2, g1);

    // ---- layer 1: P=B -> writes P=A; rec.zw: L0 -> L1 emb; xb0 -> d_out ----
    fused_kernel<true, true, true><<<bgrid, blk, 0, stream>>>(
        rec, b_off, PrB, PcB, g1,
        eW1 + 304, eB1 + 16, eW2 + 32, eB2 + 2,
        xb0, nW1 + 176, nB1 + 16, nW2 + 128, nB2 + 8,
        eW1 + 608, PrA, PcA, (float*)out, sums + 16);
    glob_kernel<<<1, 64, 0, stream>>>(sums + 16, g1, gW1 + 176, gB1 + 16, gW2 + 16, gB2 + 1, g2);

    // ---- layer 2: P=A; no rec rewrite, no P out; d_out -> d_out ----
    fused_kernel<false, false, false><<<bgrid, blk, 0, stream>>>(
        rec, b_off, PrA, PcA, g2,
        eW1 + 608, eB1 + 32, eW2 + 64, eB2 + 4,
        (float*)out, nW1 + 352, nB1 + 32, nW2 + 256, nB2 + 16,
        nullptr, nullptr, nullptr, out, sums);
}